// Round 1
// baseline (587.312 us; speedup 1.0000x reference)
//
#include <hip/hip_runtime.h>
#include <hip/hip_bf16.h>

// Problem constants: B=4, S=1024, D=1024, H=16, d_k=64, MAX_REL=128 (P=257)
#define BB 4
#define SS 1024
#define DD 1024
#define HH 16
#define DK 64
#define NP 257

__device__ __forceinline__ unsigned short f32_to_bf16(float f) {
    unsigned int u = __float_as_uint(f);
    unsigned int r = (u + 0x7FFFu + ((u >> 16) & 1u)) >> 16;
    return (unsigned short)r;
}

// ---------------- Projection GEMM: out[m,n] = sum_k X[m,k]*W[n,k] + bias[n]
// M=4096, N=1024, K=1024. Tile 64x128, TK=16, 256 threads, 4x8 micro-tile.
template <bool BF16_OUT>
__global__ __launch_bounds__(256) void proj_gemm(const float* __restrict__ X,
                                                 const float* __restrict__ W,
                                                 const float* __restrict__ bias,
                                                 void* __restrict__ outv)
{
    __shared__ float As[16][68];    // k-major, padded
    __shared__ float Bs[16][132];
    const int tid = threadIdx.x;
    const int bm = blockIdx.x * 64;
    const int bn = blockIdx.y * 128;
    float acc[4][8];
    #pragma unroll
    for (int i = 0; i < 4; ++i)
        #pragma unroll
        for (int j = 0; j < 8; ++j) acc[i][j] = 0.f;

    const int tr4 = (tid >> 4) * 4;
    const int tc8 = (tid & 15) * 8;

    for (int k0 = 0; k0 < 1024; k0 += 16) {
        #pragma unroll
        for (int i = 0; i < 4; ++i) {
            int l = i * 256 + tid;          // 0..1023
            int row = l >> 4, kk = l & 15;
            As[kk][row] = X[(size_t)(bm + row) * 1024 + k0 + kk];
        }
        #pragma unroll
        for (int i = 0; i < 8; ++i) {
            int l = i * 256 + tid;          // 0..2047
            int row = l >> 4, kk = l & 15;
            Bs[kk][row] = W[(size_t)(bn + row) * 1024 + k0 + kk];
        }
        __syncthreads();
        #pragma unroll
        for (int kk = 0; kk < 16; ++kk) {
            float a[4], b[8];
            #pragma unroll
            for (int i = 0; i < 4; ++i) a[i] = As[kk][tr4 + i];
            #pragma unroll
            for (int j = 0; j < 8; ++j) b[j] = Bs[kk][tc8 + j];
            #pragma unroll
            for (int i = 0; i < 4; ++i)
                #pragma unroll
                for (int j = 0; j < 8; ++j) acc[i][j] = fmaf(a[i], b[j], acc[i][j]);
        }
        __syncthreads();
    }

    float bv[8];
    #pragma unroll
    for (int j = 0; j < 8; ++j) bv[j] = bias[bn + tc8 + j];

    #pragma unroll
    for (int i = 0; i < 4; ++i) {
        size_t off = (size_t)(bm + tr4 + i) * 1024 + bn + tc8;
        if constexpr (BF16_OUT) {
            union { unsigned short u16[8]; uint4 v; } pk;
            #pragma unroll
            for (int j = 0; j < 8; ++j) pk.u16[j] = f32_to_bf16(acc[i][j] + bv[j]);
            *reinterpret_cast<uint4*>((unsigned short*)outv + off) = pk.v;
        } else {
            float* op = (float*)outv + off;
            float4 v0 = {acc[i][0] + bv[0], acc[i][1] + bv[1], acc[i][2] + bv[2], acc[i][3] + bv[3]};
            float4 v1 = {acc[i][4] + bv[4], acc[i][5] + bv[5], acc[i][6] + bv[6], acc[i][7] + bv[7]};
            *reinterpret_cast<float4*>(op) = v0;
            *reinterpret_cast<float4*>(op + 4) = v1;
        }
    }
}

// ---------------- q_mean[b,s,d] = (1/H) sum_h q[b,s,h*64+d]
__global__ __launch_bounds__(256) void qmean_kernel(const float* __restrict__ qf,
                                                    float* __restrict__ qmean)
{
    int idx = blockIdx.x * 256 + threadIdx.x;     // B*S*DK = 262144
    int d = idx & 63;
    size_t bs = (size_t)(idx >> 6);
    float s = 0.f;
    #pragma unroll
    for (int h = 0; h < HH; ++h) s += qf[bs * 1024 + h * 64 + d];
    qmean[idx] = s * (1.0f / 16.0f);
}

// ---------------- rel_dot[b,i,p] = scale * dot(q_mean[b,i], rel_table[p])
__global__ __launch_bounds__(256) void reldot_kernel(const float* __restrict__ qmean,
                                                     const float* __restrict__ relk,
                                                     float* __restrict__ reldot)
{
    __shared__ __align__(16) float qm[64];
    const int bi = blockIdx.x;                    // b*S + i, 4096 blocks
    if (threadIdx.x < 64) qm[threadIdx.x] = qmean[(size_t)bi * 64 + threadIdx.x];
    __syncthreads();
    const float4* qm4 = reinterpret_cast<const float4*>(qm);
    for (int p = threadIdx.x; p < NP; p += 256) {
        const float4* rk4 = reinterpret_cast<const float4*>(relk + (size_t)p * 64);
        float s0 = 0.f, s1 = 0.f, s2 = 0.f, s3 = 0.f;
        #pragma unroll
        for (int d4 = 0; d4 < 16; ++d4) {
            float4 a = qm4[d4];
            float4 b = rk4[d4];
            s0 = fmaf(a.x, b.x, s0);
            s1 = fmaf(a.y, b.y, s1);
            s2 = fmaf(a.z, b.z, s2);
            s3 = fmaf(a.w, b.w, s3);
        }
        reldot[(size_t)bi * NP + p] = (s0 + s1 + s2 + s3) * 0.125f;
    }
}

// ---------------- Fused scores + rel + mask + softmax + write
// grid (S/8, H, B), block 256 (4 waves). 8 rows per block.
__global__ __launch_bounds__(256) void attn_kernel(const float* __restrict__ qf,
                                                   const unsigned short* __restrict__ kbf,
                                                   const int* __restrict__ mask,
                                                   const float* __restrict__ reldot,
                                                   float* __restrict__ out)
{
    const int rt = blockIdx.x;                    // 0..127
    const int h  = blockIdx.y;                    // 0..15
    const int b  = blockIdx.z;                    // 0..3
    __shared__ __align__(16) float sc[8][1024];
    const int tid = threadIdx.x;
    const int i0 = rt * 8;
    const float* qbase = qf + ((size_t)(b * 1024 + i0)) * 1024 + h * 64;

    #pragma unroll 1
    for (int jb = 0; jb < 1024; jb += 256) {
        const int j = jb + tid;
        const unsigned short* kp = kbf + ((size_t)(b * 1024 + j)) * 1024 + h * 64;
        float kv[64];
        #pragma unroll
        for (int c = 0; c < 4; ++c) {
            uint4 raw = *reinterpret_cast<const uint4*>(kp + c * 16);
            uint4 raw2 = *reinterpret_cast<const uint4*>(kp + c * 16 + 8);
            unsigned int w;
            w = raw.x;  kv[c*16+ 0] = __uint_as_float(w << 16); kv[c*16+ 1] = __uint_as_float(w & 0xFFFF0000u);
            w = raw.y;  kv[c*16+ 2] = __uint_as_float(w << 16); kv[c*16+ 3] = __uint_as_float(w & 0xFFFF0000u);
            w = raw.z;  kv[c*16+ 4] = __uint_as_float(w << 16); kv[c*16+ 5] = __uint_as_float(w & 0xFFFF0000u);
            w = raw.w;  kv[c*16+ 6] = __uint_as_float(w << 16); kv[c*16+ 7] = __uint_as_float(w & 0xFFFF0000u);
            w = raw2.x; kv[c*16+ 8] = __uint_as_float(w << 16); kv[c*16+ 9] = __uint_as_float(w & 0xFFFF0000u);
            w = raw2.y; kv[c*16+10] = __uint_as_float(w << 16); kv[c*16+11] = __uint_as_float(w & 0xFFFF0000u);
            w = raw2.z; kv[c*16+12] = __uint_as_float(w << 16); kv[c*16+13] = __uint_as_float(w & 0xFFFF0000u);
            w = raw2.w; kv[c*16+14] = __uint_as_float(w << 16); kv[c*16+15] = __uint_as_float(w & 0xFFFF0000u);
        }
        #pragma unroll
        for (int r = 0; r < 8; ++r) {
            const float* qr = qbase + (size_t)r * 1024;   // wave-uniform -> scalar loads
            float s0 = 0.f, s1 = 0.f, s2 = 0.f, s3 = 0.f;
            #pragma unroll
            for (int d = 0; d < 64; d += 4) {
                s0 = fmaf(qr[d + 0], kv[d + 0], s0);
                s1 = fmaf(qr[d + 1], kv[d + 1], s1);
                s2 = fmaf(qr[d + 2], kv[d + 2], s2);
                s3 = fmaf(qr[d + 3], kv[d + 3], s3);
            }
            const int i = i0 + r;
            int rel = j - i;
            rel = rel < -128 ? -128 : (rel > 128 ? 128 : rel);
            float v = ((s0 + s1) + (s2 + s3)) * 0.125f
                      + reldot[(size_t)(b * 1024 + i) * NP + rel + 128];
            if (mask[(size_t)(b * 1024 + i) * 1024 + j] == 0) v = -1e9f;
            sc[r][j] = v;
        }
    }
    __syncthreads();

    const int wv = tid >> 6, lane = tid & 63;
    #pragma unroll
    for (int rr = 0; rr < 2; ++rr) {
        const int r = wv * 2 + rr;
        float m = -3.0e38f;
        #pragma unroll
        for (int c0 = 0; c0 < 1024; c0 += 64) m = fmaxf(m, sc[r][c0 + lane]);
        #pragma unroll
        for (int off = 32; off > 0; off >>= 1) m = fmaxf(m, __shfl_xor(m, off, 64));
        float sum = 0.f;
        #pragma unroll
        for (int c0 = 0; c0 < 1024; c0 += 64) sum += __expf(sc[r][c0 + lane] - m);
        #pragma unroll
        for (int off = 32; off > 0; off >>= 1) sum += __shfl_xor(sum, off, 64);
        const float inv = 1.0f / sum;
        float* op = out + ((size_t)((b * 16 + h) * 1024 + i0 + r)) * 1024;
        #pragma unroll
        for (int n = 0; n < 4; ++n) {
            int c = n * 256 + lane * 4;
            float4 v = *reinterpret_cast<const float4*>(&sc[r][c]);
            v.x = __expf(v.x - m) * inv;
            v.y = __expf(v.y - m) * inv;
            v.z = __expf(v.z - m) * inv;
            v.w = __expf(v.w - m) * inv;
            *reinterpret_cast<float4*>(op + c) = v;
        }
    }
}

extern "C" void kernel_launch(void* const* d_in, const int* in_sizes, int n_in,
                              void* d_out, int out_size, void* d_ws, size_t ws_size,
                              hipStream_t stream) {
    const float* query = (const float*)d_in[0];
    const float* key   = (const float*)d_in[1];
    const int*   mask  = (const int*)d_in[2];
    const float* Wq    = (const float*)d_in[3];
    const float* bq    = (const float*)d_in[4];
    const float* Wk    = (const float*)d_in[5];
    const float* bk    = (const float*)d_in[6];
    const float* relk  = (const float*)d_in[7];

    char* ws = (char*)d_ws;
    float*          qf    = (float*)ws;                              // 16 MB fp32 q
    unsigned short* kbf   = (unsigned short*)(ws + (16u << 20));     // 8 MB bf16 k
    float*          qmean = (float*)(ws + (24u << 20));              // 1 MB
    float*          rdot  = (float*)(ws + (25u << 20));              // 4.21 MB
    float*          out   = (float*)d_out;

    dim3 pg(64, 8);
    proj_gemm<false><<<pg, 256, 0, stream>>>(query, Wq, bq, (void*)qf);
    proj_gemm<true ><<<pg, 256, 0, stream>>>(key,   Wk, bk, (void*)kbf);
    qmean_kernel<<<1024, 256, 0, stream>>>(qf, qmean);
    reldot_kernel<<<4096, 256, 0, stream>>>(qmean, relk, rdot);
    attn_kernel<<<dim3(128, 16, 4), 256, 0, stream>>>(qf, kbf, mask, rdot, out);
}

// Round 2
// 200.541 us; speedup vs baseline: 2.9286x; 2.9286x over previous
//
#include <hip/hip_runtime.h>
#include <hip/hip_bf16.h>

// B=4, S=1024, D=1024, H=16, d_k=64, MAX_REL=128 (NP=257)
#define NP 257

typedef __attribute__((ext_vector_type(8))) short short8;
typedef __attribute__((ext_vector_type(4))) float f32x4;

__device__ __forceinline__ unsigned short f32_to_bf16(float f) {
    unsigned int u = __float_as_uint(f);
    unsigned int r = (u + 0x7FFFu + ((u >> 16) & 1u)) >> 16;
    return (unsigned short)r;
}
__device__ __forceinline__ float bf16_to_f32(unsigned short u) {
    return __uint_as_float(((unsigned int)u) << 16);
}

// ---------------- fp32 -> bf16 pack, 8 elems/thread
__global__ __launch_bounds__(256) void cvt_bf16(const float* __restrict__ src,
                                                unsigned short* __restrict__ dst, int n8)
{
    int i = blockIdx.x * 256 + threadIdx.x;
    if (i >= n8) return;
    const float4* s = reinterpret_cast<const float4*>(src) + (size_t)i * 2;
    float4 a = s[0], b = s[1];
    union { unsigned short u[8]; uint4 v; } p;
    p.u[0] = f32_to_bf16(a.x); p.u[1] = f32_to_bf16(a.y);
    p.u[2] = f32_to_bf16(a.z); p.u[3] = f32_to_bf16(a.w);
    p.u[4] = f32_to_bf16(b.x); p.u[5] = f32_to_bf16(b.y);
    p.u[6] = f32_to_bf16(b.z); p.u[7] = f32_to_bf16(b.w);
    reinterpret_cast<uint4*>(dst)[i] = p.v;
}

// ---------------- MFMA projection: out[m,n] = sum_k X[m,k]*W[n,k] + bias[n]
// M=4096 N=1024 K=1024. Tile 64x64x64, 256 thr (4 waves, 2x2), bf16 in/out fp32 acc.
// LDS tiles are 16B-chunked with XOR swizzle (chunk ^= row&7); global_load_lds writes
// linearly, so the swizzle is applied by permuting the per-lane GLOBAL source chunk.
__global__ __launch_bounds__(256) void proj_mfma(const unsigned short* __restrict__ Xb,
                                                 const unsigned short* __restrict__ Wb,
                                                 const float* __restrict__ bias,
                                                 unsigned short* __restrict__ outb)
{
    __shared__ unsigned short As[4096];   // 64 rows x 8 chunks x 8 bf16
    __shared__ unsigned short Bs[4096];
    const int tid = threadIdx.x;
    const int lane = tid & 63;
    const int w = tid >> 6;
    const int wi = w >> 1, wj = w & 1;
    const int bm = blockIdx.x * 64, bn = blockIdx.y * 64;

    f32x4 acc[2][2];
    #pragma unroll
    for (int i = 0; i < 2; ++i)
        #pragma unroll
        for (int j = 0; j < 2; ++j) acc[i][j] = (f32x4){0.f, 0.f, 0.f, 0.f};

    // staging slots: f = it*256 + w*64 + lane; row = f>>3; phys chunk = f&7;
    // logical chunk feeding that slot = (f&7) ^ (row&7)
    const int f0 = w * 64 + lane, f1 = f0 + 256;
    const int row0 = f0 >> 3, cl0 = (f0 & 7) ^ (row0 & 7);
    const int row1 = f1 >> 3, cl1 = (f1 & 7) ^ (row1 & 7);
    const size_t gaA0 = (size_t)(bm + row0) * 1024 + cl0 * 8;
    const size_t gaA1 = (size_t)(bm + row1) * 1024 + cl1 * 8;
    const size_t gaB0 = (size_t)(bn + row0) * 1024 + cl0 * 8;
    const size_t gaB1 = (size_t)(bn + row1) * 1024 + cl1 * 8;
    const int ldsA0 = w * 512, ldsA1 = 2048 + w * 512;   // ushort offsets (slotbase*8)

    const int r15 = lane & 15, g = lane >> 4;

    for (int kt = 0; kt < 16; ++kt) {
        const int k0 = kt * 64;
        __builtin_amdgcn_global_load_lds(
            (const __attribute__((address_space(1))) void*)(Xb + gaA0 + k0),
            (__attribute__((address_space(3))) void*)(As + ldsA0), 16, 0, 0);
        __builtin_amdgcn_global_load_lds(
            (const __attribute__((address_space(1))) void*)(Xb + gaA1 + k0),
            (__attribute__((address_space(3))) void*)(As + ldsA1), 16, 0, 0);
        __builtin_amdgcn_global_load_lds(
            (const __attribute__((address_space(1))) void*)(Wb + gaB0 + k0),
            (__attribute__((address_space(3))) void*)(Bs + ldsA0), 16, 0, 0);
        __builtin_amdgcn_global_load_lds(
            (const __attribute__((address_space(1))) void*)(Wb + gaB1 + k0),
            (__attribute__((address_space(3))) void*)(Bs + ldsA1), 16, 0, 0);
        __syncthreads();

        #pragma unroll
        for (int kk = 0; kk < 2; ++kk) {
            const int c = kk * 4 + g;          // logical 16B chunk within row
            const int ra = wi * 32 + r15, ra1 = ra + 16;
            const int rb = wj * 32 + r15, rb1 = rb + 16;
            short8 a0 = *(const short8*)&As[(ra  * 8 + (c ^ (ra  & 7))) * 8];
            short8 a1 = *(const short8*)&As[(ra1 * 8 + (c ^ (ra1 & 7))) * 8];
            short8 b0 = *(const short8*)&Bs[(rb  * 8 + (c ^ (rb  & 7))) * 8];
            short8 b1 = *(const short8*)&Bs[(rb1 * 8 + (c ^ (rb1 & 7))) * 8];
            acc[0][0] = __builtin_amdgcn_mfma_f32_16x16x32_bf16(a0, b0, acc[0][0], 0, 0, 0);
            acc[0][1] = __builtin_amdgcn_mfma_f32_16x16x32_bf16(a0, b1, acc[0][1], 0, 0, 0);
            acc[1][0] = __builtin_amdgcn_mfma_f32_16x16x32_bf16(a1, b0, acc[1][0], 0, 0, 0);
            acc[1][1] = __builtin_amdgcn_mfma_f32_16x16x32_bf16(a1, b1, acc[1][1], 0, 0, 0);
        }
        __syncthreads();
    }

    // C/D: col = lane&15, row = (lane>>4)*4 + reg
    const int orow = bm + wi * 32 + (g << 2);
    const int ocol0 = bn + wj * 32 + r15;
    #pragma unroll
    for (int tj = 0; tj < 2; ++tj) {
        const int n = ocol0 + tj * 16;
        const float bv = bias[n];
        #pragma unroll
        for (int ti = 0; ti < 2; ++ti)
            #pragma unroll
            for (int r = 0; r < 4; ++r)
                outb[(size_t)(orow + ti * 16 + r) * 1024 + n] = f32_to_bf16(acc[ti][tj][r] + bv);
    }
}

// ---------------- q_mean from bf16 q
__global__ __launch_bounds__(256) void qmean_kernel(const unsigned short* __restrict__ qb,
                                                    float* __restrict__ qmean)
{
    int idx = blockIdx.x * 256 + threadIdx.x;   // 262144
    int d = idx & 63;
    size_t bs = (size_t)(idx >> 6);
    float s = 0.f;
    #pragma unroll
    for (int h = 0; h < 16; ++h) s += bf16_to_f32(qb[bs * 1024 + h * 64 + d]);
    qmean[idx] = s * 0.0625f;
}

// ---------------- rel_dot[b,i,p] = scale * dot(q_mean[b,i], rel_table[p])
__global__ __launch_bounds__(256) void reldot_kernel(const float* __restrict__ qmean,
                                                     const float* __restrict__ relk,
                                                     float* __restrict__ reldot)
{
    __shared__ __align__(16) float qm[64];
    const int bi = blockIdx.x;                  // 4096
    if (threadIdx.x < 64) qm[threadIdx.x] = qmean[(size_t)bi * 64 + threadIdx.x];
    __syncthreads();
    const float4* qm4 = reinterpret_cast<const float4*>(qm);
    for (int p = threadIdx.x; p < NP; p += 256) {
        const float4* rk4 = reinterpret_cast<const float4*>(relk + (size_t)p * 64);
        float s0 = 0.f, s1 = 0.f, s2 = 0.f, s3 = 0.f;
        #pragma unroll
        for (int d4 = 0; d4 < 16; ++d4) {
            float4 a = qm4[d4];
            float4 b = rk4[d4];
            s0 = fmaf(a.x, b.x, s0);
            s1 = fmaf(a.y, b.y, s1);
            s2 = fmaf(a.z, b.z, s2);
            s3 = fmaf(a.w, b.w, s3);
        }
        reldot[(size_t)bi * NP + p] = (s0 + s1 + s2 + s3) * 0.125f;
    }
}

// ---------------- MFMA attention: 16 q-rows x 1024 cols per block, one (b,h)
// QK^T via mfma 16x16x32; scores fp32 in LDS (col XOR-swizzled); wave softmax.
__global__ __launch_bounds__(256) void attn_mfma(const unsigned short* __restrict__ qb,
                                                 const unsigned short* __restrict__ kb,
                                                 const int* __restrict__ mask,
                                                 const float* __restrict__ rdot,
                                                 float* __restrict__ out)
{
    __shared__ float sc[16][1024];              // 64 KB, access col ^ ((row&7)<<4)
    const int i0 = blockIdx.x * 16;
    const int h = blockIdx.y, b = blockIdx.z;
    const int tid = threadIdx.x, lane = tid & 63, w = tid >> 6;
    const int r15 = lane & 15, g = lane >> 4;
    const size_t qkbase = ((size_t)b << 20) + h * 64;

    // A frags: Q rows i0..i0+15, k window {0..31},{32..63}
    short8 af0, af1;
    {
        const unsigned short* qp = qb + qkbase + (size_t)(i0 + r15) * 1024 + 8 * g;
        af0 = *(const short8*)(qp);
        af1 = *(const short8*)(qp + 32);
    }

    const int n0w = w * 256;
    #pragma unroll 4
    for (int jt = 0; jt < 16; ++jt) {
        const int n0 = n0w + jt * 16;
        const unsigned short* kp = kb + qkbase + (size_t)(n0 + r15) * 1024 + 8 * g;
        short8 bf0 = *(const short8*)(kp);
        short8 bf1 = *(const short8*)(kp + 32);
        f32x4 acc = (f32x4){0.f, 0.f, 0.f, 0.f};
        acc = __builtin_amdgcn_mfma_f32_16x16x32_bf16(af0, bf0, acc, 0, 0, 0);
        acc = __builtin_amdgcn_mfma_f32_16x16x32_bf16(af1, bf1, acc, 0, 0, 0);
        const int j = n0 + r15;
        #pragma unroll
        for (int r = 0; r < 4; ++r) {
            const int rowl = (g << 2) + r;
            const int i = i0 + rowl;
            int d = j - i;
            d = d < -128 ? -128 : (d > 128 ? 128 : d);
            float v = acc[r] * 0.125f + rdot[(size_t)(b * 1024 + i) * NP + d + 128];
            if (mask[((size_t)(b * 1024 + i) << 10) + j] == 0) v = -1e9f;
            sc[rowl][j ^ ((rowl & 7) << 4)] = v;
        }
    }
    __syncthreads();

    // softmax: wave w -> rows 4w..4w+3
    #pragma unroll
    for (int rr = 0; rr < 4; ++rr) {
        const int r = w * 4 + rr;
        const int xr = (r & 7) << 4;
        float m = -3.0e38f;
        #pragma unroll
        for (int c0 = 0; c0 < 1024; c0 += 64) m = fmaxf(m, sc[r][(c0 + lane) ^ xr]);
        #pragma unroll
        for (int off = 32; off > 0; off >>= 1) m = fmaxf(m, __shfl_xor(m, off, 64));
        float sum = 0.f;
        #pragma unroll
        for (int c0 = 0; c0 < 1024; c0 += 64) sum += __expf(sc[r][(c0 + lane) ^ xr] - m);
        #pragma unroll
        for (int off = 32; off > 0; off >>= 1) sum += __shfl_xor(sum, off, 64);
        const float inv = 1.0f / sum;
        float* op = out + (((size_t)((b * 16 + h) * 1024 + i0 + r)) << 10);
        #pragma unroll
        for (int n = 0; n < 4; ++n) {
            const int c = n * 256 + lane * 4;
            float4 v = *reinterpret_cast<const float4*>(&sc[r][c ^ xr]);
            v.x = __expf(v.x - m) * inv;
            v.y = __expf(v.y - m) * inv;
            v.z = __expf(v.z - m) * inv;
            v.w = __expf(v.w - m) * inv;
            *reinterpret_cast<float4*>(op + c) = v;
        }
    }
}

extern "C" void kernel_launch(void* const* d_in, const int* in_sizes, int n_in,
                              void* d_out, int out_size, void* d_ws, size_t ws_size,
                              hipStream_t stream) {
    const float* query = (const float*)d_in[0];
    const float* key   = (const float*)d_in[1];
    const int*   mask  = (const int*)d_in[2];
    const float* Wq    = (const float*)d_in[3];
    const float* bq    = (const float*)d_in[4];
    const float* Wk    = (const float*)d_in[5];
    const float* bk    = (const float*)d_in[6];
    const float* relk  = (const float*)d_in[7];

    char* ws = (char*)d_ws;
    unsigned short* qB     = (unsigned short*)(ws);                  // 8 MB  q bf16
    unsigned short* kB     = (unsigned short*)(ws + (8u  << 20));    // 8 MB  k bf16
    unsigned short* queryb = (unsigned short*)(ws + (16u << 20));    // 8 MB
    unsigned short* keyb   = (unsigned short*)(ws + (24u << 20));    // 8 MB
    unsigned short* Wqb    = (unsigned short*)(ws + (32u << 20));    // 2 MB
    unsigned short* Wkb    = (unsigned short*)(ws + (34u << 20));    // 2 MB
    float*          qmean  = (float*)(ws + (36u << 20));             // 1 MB
    float*          rdot   = (float*)(ws + (37u << 20));             // 4.21 MB
    float*          out    = (float*)d_out;

    cvt_bf16<<<2048, 256, 0, stream>>>(query, queryb, 524288);
    cvt_bf16<<<2048, 256, 0, stream>>>(key,   keyb,   524288);
    cvt_bf16<<<512,  256, 0, stream>>>(Wq,    Wqb,    131072);
    cvt_bf16<<<512,  256, 0, stream>>>(Wk,    Wkb,    131072);

    dim3 pg(64, 16);
    proj_mfma<<<pg, 256, 0, stream>>>(queryb, Wqb, bq, qB);
    proj_mfma<<<pg, 256, 0, stream>>>(keyb,   Wkb, bk, kB);

    qmean_kernel<<<1024, 256, 0, stream>>>(qB, qmean);
    reldot_kernel<<<4096, 256, 0, stream>>>(qmean, relk, rdot);

    attn_mfma<<<dim3(64, 16, 4), 256, 0, stream>>>(qB, kB, mask, rdot, out);
}